// Round 6
// baseline (1268.294 us; speedup 1.0000x reference)
//
#include <hip/hip_runtime.h>
#include <math.h>

// FNO3D: B=8, C=3, H=W=64, T=32, WIDTH=32, modes 8x8x8 (4 corners), 4 layers.
// Round 6: fuse kernels process (t, t+16) point-pairs per thread.
//  - spectral irfft-t via even/odd-k split: one eval serves both t's
//  - packed fp32 (<2 x float> -> v_pk_fma_f32) for matmuls + gelu polynomial
//  - Goertzel t-DFT in two spl-half passes reusing the same LDS union
//
// ws floats: X 33,554,432 | T1 16,777,216 | T2 4,194,304 | T3 1,048,576 | T4 1,048,576

#define TWO_PI 6.2831853071795864769f

typedef float v2f __attribute__((ext_vector_type(2)));

__device__ __forceinline__ v2f make2(float x) { v2f r; r.x = x; r.y = x; return r; }
__device__ __forceinline__ v2f fma2(v2f a, v2f b, v2f c) { return __builtin_elementwise_fma(a, b, c); }

// gelu via A&S 7.1.26 erf (|err|<=1.5e-7), packed over two values.
__device__ __forceinline__ v2f gelu2(v2f v) {
    v2f u = v * 0.70710678118654752f;
    v2f a = __builtin_elementwise_abs(u);
    v2f den = fma2(a, make2(0.3275911f), make2(1.0f));
    v2f t; t.x = __builtin_amdgcn_rcpf(den.x); t.y = __builtin_amdgcn_rcpf(den.y);
    v2f p = t * (0.254829592f + t * (-0.284496736f + t * (1.421413741f +
            t * (-1.453152027f + t * 1.061405429f))));
    v2f e; e.x = __expf(-u.x * u.x); e.y = __expf(-u.y * u.y);
    v2f m = fma2(-p, e, make2(1.0f));
    v2f erfu = __builtin_elementwise_copysign(m, u);
    return 0.5f * v * (1.0f + erfu);
}

__device__ __forceinline__ float gelu_fast(float v) {
    float u = v * 0.70710678118654752f;
    float a = fabsf(u);
    float t = __builtin_amdgcn_rcpf(fmaf(0.3275911f, a, 1.0f));
    float p = t * (0.254829592f + t * (-0.284496736f + t * (1.421413741f +
              t * (-1.453152027f + t * 1.061405429f))));
    float e = __expf(-u * u);
    float m = fmaf(-p, e, 1.0f);
    float erfu = copysignf(m, u);
    return 0.5f * v * (1.0f + erfu);
}

// Goertzel constants for N=32, k=0..7
#define GOERTZEL_CONSTS \
    const float C2[8] = {2.0f, 1.9615705608f, 1.8477590650f, 1.6629392246f, \
                         1.4142135624f, 1.1111404660f, 0.7653668647f, 0.3901806440f}; \
    const float CK[8] = {1.0f, 0.9807852804f, 0.9238795325f, 0.8314696123f, \
                         0.7071067812f, 0.5555702330f, 0.3826834324f, 0.1950903220f}; \
    const float SK[8] = {0.0f, 0.1950903220f, 0.3826834324f, 0.5555702330f, \
                         0.7071067812f, 0.8314696123f, 0.9238795325f, 0.9807852804f};

// doubled twiddles e^{+j 2pi k t/32}: ck2[k]=2cos, sk2[k]=2sin, k=1..7
#define MAKE_TWIDDLES(t) \
    float ck2[8], sk2[8]; \
    float c1, s1v; sincosf((t) * (TWO_PI / 32.0f), &s1v, &c1); \
    ck2[1] = 2.0f * c1; sk2[1] = 2.0f * s1v; \
    _Pragma("unroll") \
    for (int k = 2; k < 8; ++k) { \
        float nc = ck2[k-1] * c1 - sk2[k-1] * s1v; \
        float ns = sk2[k-1] * c1 + ck2[k-1] * s1v; \
        ck2[k] = nc; sk2[k] = ns; \
    }

// ---- lift: x_t + grid -> p conv -> X [b][sp][t][c]; fused Goertzel -> T1 ----
__global__ __launch_bounds__(256) void k_lift(const float* __restrict__ xt,
                                              const float* __restrict__ pw,
                                              const float* __restrict__ pb,
                                              float* __restrict__ X,
                                              float2* __restrict__ T1) {
    __shared__ float xs[8448];          // [spl8][t32] rows of 33 (pad)
    int g = blockIdx.x;                 // b*512 + spt ; 4096 blocks
    int spt = g & 511, b = g >> 9;
    int sp0 = spt * 8;
    int y = sp0 >> 6, x0 = sp0 & 63;
    int tid = threadIdx.x;
    int t = tid & 31, spl = tid >> 5;
    int sp = sp0 + spl;
    float a0 = xt[(b * 3 + 0) * 4096 + sp];
    float a1 = xt[(b * 3 + 1) * 4096 + sp];
    float a2 = xt[(b * 3 + 2) * 4096 + sp];
    float gy = y * (1.0f / 63.0f), gx = (x0 + spl) * (1.0f / 63.0f), gt = t * (1.0f / 31.0f);
    float v[32];
    #pragma unroll
    for (int c = 0; c < 32; ++c) {
        const float* w = pw + c * 6;
        v[c] = pb[c] + w[0] * a0 + w[1] * a1 + w[2] * a2
             + w[3] * gy + w[4] * gx + w[5] * gt;
    }
    float* xg = X + (((long)(b * 4096 + sp)) * 32 + t) * 32;
    #pragma unroll
    for (int j = 0; j < 8; ++j)
        ((float4*)xg)[j] = make_float4(v[4*j], v[4*j+1], v[4*j+2], v[4*j+3]);
    float* row = xs + (spl * 32 + t) * 33;
    #pragma unroll
    for (int c = 0; c < 32; ++c) row[c] = v[c];
    __syncthreads();
    int c = tid & 31, sl = tid >> 5;
    GOERTZEL_CONSTS
    float s1[8], s2[8];
    #pragma unroll
    for (int k = 0; k < 8; ++k) { s1[k] = 0.f; s2[k] = 0.f; }
    const float* col = xs + (sl * 32) * 33 + c;
    for (int tt = 0; tt < 32; ++tt) {
        float xv = col[tt * 33];
        #pragma unroll
        for (int k = 0; k < 8; ++k) {
            float s0 = xv + C2[k] * s1[k] - s2[k];
            s2[k] = s1[k]; s1[k] = s0;
        }
    }
    float2* ob = T1 + ((long)(b * 32 + c) * 4096 + sp0 + sl) * 8;
    #pragma unroll
    for (int k = 0; k < 8; ++k)
        ob[k] = make_float2(CK[k] * s1[k] - s2[k], SK[k] * s1[k]);
}

// ---------------- forward x-DFT: T1 -> T2 (16 modes) ----------------
__global__ __launch_bounds__(256) void k_xdft(const float2* __restrict__ T1, float2* __restrict__ T2) {
    __shared__ float2 s[1024];
    __shared__ float2 tw[64];
    int g = blockIdx.x;              // bc*32 + ypair ; 8192 blocks
    int ypair = g & 31; int bc = g >> 5;
    long base = ((long)bc * 64 + ypair * 2) * 512;
    int tid = threadIdx.x;
    for (int k = tid; k < 1024; k += 256) s[k] = T1[base + k];
    if (tid < 64) { float sn, cs; sincosf(tid * (TWO_PI / 64.0f), &sn, &cs); tw[tid] = make_float2(cs, sn); }
    __syncthreads();
    int half = tid >> 7, jj = tid & 127;
    int kxi = jj >> 3, kt = jj & 7;
    int kx = kxi < 8 ? kxi : kxi + 48;
    const float2* row = s + half * 512;
    float sr = 0.f, si = 0.f;
    for (int x = 0; x < 64; ++x) {
        float2 w = tw[(kx * x) & 63];
        float2 a = row[x * 8 + kt];
        sr += a.x * w.x + a.y * w.y;
        si += a.y * w.x - a.x * w.y;
    }
    T2[((long)bc * 64 + ypair * 2 + half) * 128 + jj] = make_float2(sr, si);
}

// ---------------- forward y-DFT: T2 -> T3 (16 modes) ----------------
__global__ __launch_bounds__(128) void k_ydft(const float2* __restrict__ T2, float2* __restrict__ T3) {
    __shared__ float2 s[512];
    __shared__ float2 tw[64];
    int g = blockIdx.x;              // bc*16 + kx ; 4096 blocks
    int kx = g & 15; int bc = g >> 4;
    int tid = threadIdx.x;
    for (int k = tid; k < 512; k += 128) {
        int y = k >> 3, kt = k & 7;
        s[k] = T2[((long)bc * 64 + y) * 128 + kx * 8 + kt];
    }
    if (tid < 64) { float sn, cs; sincosf(tid * (TWO_PI / 64.0f), &sn, &cs); tw[tid] = make_float2(cs, sn); }
    __syncthreads();
    int kyi = tid >> 3, kt = tid & 7;
    int ky = kyi < 8 ? kyi : kyi + 48;
    float sr = 0.f, si = 0.f;
    for (int y = 0; y < 64; ++y) {
        float2 w = tw[(ky * y) & 63];
        float2 a = s[y * 8 + kt];
        sr += a.x * w.x + a.y * w.y;
        si += a.y * w.x - a.x * w.y;
    }
    T3[((long)bc * 256 + kyi * 16 + kx) * 8 + kt] = make_float2(sr, si);
}

// -------- mode mix (mode-major, b-loop amortizes weight reads) --------
__global__ __launch_bounds__(256) void k_mix2(const float2* __restrict__ T3,
                                              const float* __restrict__ wr,
                                              const float* __restrict__ wi,
                                              float2* __restrict__ T4, int layer) {
    __shared__ float2 s[2304];       // [i=32][b=8] rows padded to 9 f2
    int mode = blockIdx.x;           // 256 blocks
    int kyi = mode >> 4, kxi = mode & 15;
    int tid = threadIdx.x;
    {
        int bb = tid >> 5, i = tid & 31;
        const float2* src = T3 + ((long)(bb * 32 + i) * 256 + mode) * 8;
        float2* dst = s + (i * 8 + bb) * 9;
        #pragma unroll
        for (int k = 0; k < 8; ++k) dst[k] = src[k];
    }
    __syncthreads();
    int corner = (kyi >= 8 ? 1 : 0) + (kxi >= 8 ? 2 : 0);
    long wbase = (long)(layer * 4 + corner) * 524288 + (long)(kyi & 7) * 64 + (long)(kxi & 7) * 8;
    int o = tid >> 3, kt = tid & 7;
    long wb = wbase + (long)o * 512 + kt;
    float2 acc[8];
    #pragma unroll
    for (int bb = 0; bb < 8; ++bb) acc[bb] = make_float2(0.f, 0.f);
    for (int i = 0; i < 32; ++i) {
        float r = wr[wb + (long)i * 16384], im = wi[wb + (long)i * 16384];
        #pragma unroll
        for (int bb = 0; bb < 8; ++bb) {
            float2 a = s[(i * 8 + bb) * 9 + kt];
            acc[bb].x += a.x * r - a.y * im;
            acc[bb].y += a.x * im + a.y * r;
        }
    }
    #pragma unroll
    for (int bb = 0; bb < 8; ++bb)
        T4[((long)(bb * 32 + o) * 256 + mode) * 8 + kt] = acc[bb];
}

// ---------------- inverse y: T4 -> T2 space ----------------
__global__ __launch_bounds__(256) void k_invy(const float2* __restrict__ T4, float2* __restrict__ T5) {
    __shared__ float2 s[128];
    __shared__ float2 tw[64];
    int g = blockIdx.x;              // bc*16 + kx ; 4096 blocks
    int kx = g & 15; int bc = g >> 4;
    int tid = threadIdx.x;
    if (tid < 128) {
        int kyi = tid >> 3, kt = tid & 7;
        s[tid] = T4[((long)bc * 256 + kyi * 16 + kx) * 8 + kt];
    } else if (tid < 192) {
        int m = tid - 128; float sn, cs; sincosf(m * (TWO_PI / 64.0f), &sn, &cs); tw[m] = make_float2(cs, sn);
    }
    __syncthreads();
    for (int r = 0; r < 2; ++r) {
        int j = tid + r * 256;
        int y = j >> 3, kt = j & 7;
        float sr = 0.f, si = 0.f;
        for (int kyi = 0; kyi < 16; ++kyi) {
            int ky = kyi < 8 ? kyi : kyi + 48;
            float2 w = tw[(ky * y) & 63];
            float2 a = s[kyi * 8 + kt];
            sr += a.x * w.x - a.y * w.y;
            si += a.y * w.x + a.x * w.y;
        }
        T5[((long)bc * 64 + y) * 128 + kx * 8 + kt] = make_float2(sr, si);
    }
}

// ---------------- inverse x: T2 space -> T1 space (T6) ----------------
__global__ __launch_bounds__(256) void k_invx(const float2* __restrict__ T5, float2* __restrict__ T6) {
    __shared__ float2 s[128];
    __shared__ float2 tw[64];
    int g = blockIdx.x;              // bc*64 + y ; 16384 blocks
    int tid = threadIdx.x;
    if (tid < 128) {
        s[tid] = T5[(long)g * 128 + tid];
    } else if (tid < 192) {
        int m = tid - 128; float sn, cs; sincosf(m * (TWO_PI / 64.0f), &sn, &cs); tw[m] = make_float2(cs, sn);
    }
    __syncthreads();
    for (int r = 0; r < 2; ++r) {
        int j = tid + r * 256;
        int x = j >> 3, kt = j & 7;
        float sr = 0.f, si = 0.f;
        for (int kxi = 0; kxi < 16; ++kxi) {
            int kx = kxi < 8 ? kxi : kxi + 48;
            float2 w = tw[(kx * x) & 63];
            float2 a = s[kxi * 8 + kt];
            sr += a.x * w.x - a.y * w.y;
            si += a.y * w.x + a.x * w.y;
        }
        T6[(long)g * 512 + j] = make_float2(sr, si);
    }
}

// ---- fuse2: (t,t+16)-paired pointwise + E/O spec + gelu2; Goertzel 2-pass -> T1 ----
__global__ __launch_bounds__(256) void k_fuse2(float* __restrict__ X, const float2* __restrict__ T6,
                                               const float* __restrict__ pww,
                                               const float* __restrict__ pwb,
                                               float2* __restrict__ T1, int layer) {
    __shared__ float smem[8448];     // union: ts 4096 f2 (32 KB) / xs 8448 f
    float2* ts = (float2*)smem;
    int g = blockIdx.x;              // b*256 + spt ; 2048 blocks
    int spt = g & 255, b = g >> 8;
    int sp0 = spt * 16;
    int tid = threadIdx.x;
    const float S = 1.0f / 131072.0f;
    #pragma unroll
    for (int p = 0; p < 2; ++p) {    // stage spectral tile pre-scaled
        int idx = tid + p * 256;     // 512 (o,spl) chunks
        int o = idx >> 4, spl8 = idx & 15;
        const float4* src = (const float4*)(T6 + ((long)(b * 32 + o) * 4096 + sp0 + spl8) * 8);
        float4* dst = (float4*)(ts + (o * 16 + spl8) * 8);
        #pragma unroll
        for (int j = 0; j < 4; ++j) {
            float4 q = src[j];
            dst[j] = make_float4(q.x * S, q.y * S, q.z * S, q.w * S);
        }
    }
    __syncthreads();
    int t = tid & 15, spl = tid >> 4;
    int sp = sp0 + spl;
    MAKE_TWIDDLES(t)
    const float* wl = pww + layer * 1024;
    const float* bl = pwb + layer * 32;
    float* xg0 = X + (((long)(b * 4096 + sp)) * 32 + t) * 32;
    float* xg1 = xg0 + 512;          // t+16
    v2f acc[32];
    #pragma unroll
    for (int o = 0; o < 32; ++o) acc[o] = make2(bl[o]);
    #pragma unroll
    for (int h = 0; h < 2; ++h) {
        v2f xv[16];
        #pragma unroll
        for (int j = 0; j < 4; ++j) {
            float4 q0 = ((const float4*)xg0)[h * 4 + j];
            float4 q1 = ((const float4*)xg1)[h * 4 + j];
            xv[4*j+0].x = q0.x; xv[4*j+0].y = q1.x;
            xv[4*j+1].x = q0.y; xv[4*j+1].y = q1.y;
            xv[4*j+2].x = q0.z; xv[4*j+2].y = q1.z;
            xv[4*j+3].x = q0.w; xv[4*j+3].y = q1.w;
        }
        #pragma unroll
        for (int i = 0; i < 16; ++i) {
            #pragma unroll
            for (int o = 0; o < 32; ++o)
                acc[o] = fma2(make2(wl[o * 32 + h * 16 + i]), xv[i], acc[o]);
        }
    }
    #pragma unroll
    for (int o = 0; o < 32; ++o) {   // E/O spec: one eval serves t and t+16
        const float4* f4 = (const float4*)(ts + (o * 16 + spl) * 8);
        float4 q0 = f4[0], q1f = f4[1], q2f = f4[2], q3f = f4[3];
        float E = q0.x, O = 0.f;
        O += q0.z * ck2[1] - q0.w * sk2[1];
        E += q1f.x * ck2[2] - q1f.y * sk2[2];
        O += q1f.z * ck2[3] - q1f.w * sk2[3];
        E += q2f.x * ck2[4] - q2f.y * sk2[4];
        O += q2f.z * ck2[5] - q2f.w * sk2[5];
        E += q3f.x * ck2[6] - q3f.y * sk2[6];
        O += q3f.z * ck2[7] - q3f.w * sk2[7];
        v2f spr; spr.x = E + O; spr.y = E - O;
        acc[o] = gelu2(acc[o] + spr);
    }
    #pragma unroll
    for (int j = 0; j < 8; ++j) {
        ((float4*)xg0)[j] = make_float4(acc[4*j].x, acc[4*j+1].x, acc[4*j+2].x, acc[4*j+3].x);
        ((float4*)xg1)[j] = make_float4(acc[4*j].y, acc[4*j+1].y, acc[4*j+2].y, acc[4*j+3].y);
    }
    // Goertzel t-DFT for next layer, two spl-half passes sharing xs
    GOERTZEL_CONSTS
    #pragma unroll
    for (int p = 0; p < 2; ++p) {
        __syncthreads();
        if ((spl >> 3) == p) {
            int sl = spl & 7;
            float* r0 = smem + (sl * 32 + t) * 33;
            float* r1 = smem + (sl * 32 + t + 16) * 33;
            #pragma unroll
            for (int c = 0; c < 32; ++c) { r0[c] = acc[c].x; r1[c] = acc[c].y; }
        }
        __syncthreads();
        int c = tid & 31, sl = tid >> 5;
        float s1[8], s2[8];
        #pragma unroll
        for (int k = 0; k < 8; ++k) { s1[k] = 0.f; s2[k] = 0.f; }
        const float* col = smem + (sl * 32) * 33 + c;
        for (int tt = 0; tt < 32; ++tt) {
            float xv = col[tt * 33];
            #pragma unroll
            for (int k = 0; k < 8; ++k) {
                float s0 = xv + C2[k] * s1[k] - s2[k];
                s2[k] = s1[k]; s1[k] = s0;
            }
        }
        float2* ob = T1 + ((long)(b * 32 + c) * 4096 + sp0 + p * 8 + sl) * 8;
        #pragma unroll
        for (int k = 0; k < 8; ++k)
            ob[k] = make_float2(CK[k] * s1[k] - s2[k], SK[k] * s1[k]);
    }
}

// ---- fuse2_last: layer 3 + head (q1,gelu,q2), (t,t+16)-paired -> out ----
__global__ __launch_bounds__(256) void k_fuse2_last(const float* __restrict__ X, const float2* __restrict__ T6,
                                                    const float* __restrict__ pww, const float* __restrict__ pwb,
                                                    const float* __restrict__ q1w, const float* __restrict__ q1b,
                                                    const float* __restrict__ q2w, const float* __restrict__ q2b,
                                                    float* __restrict__ out) {
    __shared__ float smem[8192];     // ts 4096 f2 / st 1632 f
    float2* ts = (float2*)smem;
    int g = blockIdx.x;              // b*256 + spt ; 2048 blocks
    int spt = g & 255, b = g >> 8;
    int sp0 = spt * 16;
    int tid = threadIdx.x;
    const float S = 1.0f / 131072.0f;
    #pragma unroll
    for (int p = 0; p < 2; ++p) {
        int idx = tid + p * 256;
        int o = idx >> 4, spl8 = idx & 15;
        const float4* src = (const float4*)(T6 + ((long)(b * 32 + o) * 4096 + sp0 + spl8) * 8);
        float4* dst = (float4*)(ts + (o * 16 + spl8) * 8);
        #pragma unroll
        for (int j = 0; j < 4; ++j) {
            float4 q = src[j];
            dst[j] = make_float4(q.x * S, q.y * S, q.z * S, q.w * S);
        }
    }
    __syncthreads();
    int t = tid & 15, spl = tid >> 4;
    int sp = sp0 + spl;
    MAKE_TWIDDLES(t)
    const float* wl = pww + 3 * 1024;
    const float* bl = pwb + 3 * 32;
    const float* xg0 = X + (((long)(b * 4096 + sp)) * 32 + t) * 32;
    const float* xg1 = xg0 + 512;
    v2f acc[32];
    #pragma unroll
    for (int o = 0; o < 32; ++o) acc[o] = make2(bl[o]);
    #pragma unroll
    for (int h = 0; h < 2; ++h) {
        v2f xv[16];
        #pragma unroll
        for (int j = 0; j < 4; ++j) {
            float4 q0 = ((const float4*)xg0)[h * 4 + j];
            float4 q1 = ((const float4*)xg1)[h * 4 + j];
            xv[4*j+0].x = q0.x; xv[4*j+0].y = q1.x;
            xv[4*j+1].x = q0.y; xv[4*j+1].y = q1.y;
            xv[4*j+2].x = q0.z; xv[4*j+2].y = q1.z;
            xv[4*j+3].x = q0.w; xv[4*j+3].y = q1.w;
        }
        #pragma unroll
        for (int i = 0; i < 16; ++i) {
            #pragma unroll
            for (int o = 0; o < 32; ++o)
                acc[o] = fma2(make2(wl[o * 32 + h * 16 + i]), xv[i], acc[o]);
        }
    }
    #pragma unroll
    for (int o = 0; o < 32; ++o) {
        const float4* f4 = (const float4*)(ts + (o * 16 + spl) * 8);
        float4 q0 = f4[0], q1f = f4[1], q2f = f4[2], q3f = f4[3];
        float E = q0.x, O = 0.f;
        O += q0.z * ck2[1] - q0.w * sk2[1];
        E += q1f.x * ck2[2] - q1f.y * sk2[2];
        O += q1f.z * ck2[3] - q1f.w * sk2[3];
        E += q2f.x * ck2[4] - q2f.y * sk2[4];
        O += q2f.z * ck2[5] - q2f.w * sk2[5];
        E += q3f.x * ck2[6] - q3f.y * sk2[6];
        O += q3f.z * ck2[7] - q3f.w * sk2[7];
        v2f spr; spr.x = E + O; spr.y = E - O;
        acc[o] = gelu2(acc[o] + spr);
    }
    // head (packed over the two t's)
    v2f o0 = make2(q2b[0]), o1 = make2(q2b[1]), o2 = make2(q2b[2]);
    #pragma unroll
    for (int j = 0; j < 64; ++j) {
        v2f h = make2(q1b[j]);
        #pragma unroll
        for (int i = 0; i < 32; ++i) h = fma2(make2(q1w[j * 32 + i]), acc[i], h);
        h = gelu2(h);
        o0 = fma2(make2(q2w[j]), h, o0);
        o1 = fma2(make2(q2w[64 + j]), h, o1);
        o2 = fma2(make2(q2w[128 + j]), h, o2);
    }
    __syncthreads();
    float* st = smem;                // [t2 32][c 3] rows of 17 (pad): conflict-free
    st[((t)      * 3 + 0) * 17 + spl] = o0.x;
    st[((t)      * 3 + 1) * 17 + spl] = o1.x;
    st[((t)      * 3 + 2) * 17 + spl] = o2.x;
    st[((t + 16) * 3 + 0) * 17 + spl] = o0.y;
    st[((t + 16) * 3 + 1) * 17 + spl] = o1.y;
    st[((t + 16) * 3 + 2) * 17 + spl] = o2.y;
    __syncthreads();
    #pragma unroll
    for (int r = 0; r < 6; ++r) {
        int m = tid + r * 256;       // 1536 outputs
        int spl2 = m & 15, u = m >> 4;   // u = t2*3 + c
        out[((long)(b * 96 + u)) * 4096 + sp0 + spl2] = st[u * 17 + spl2];
    }
}

extern "C" void kernel_launch(void* const* d_in, const int* in_sizes, int n_in,
                              void* d_out, int out_size, void* d_ws, size_t ws_size,
                              hipStream_t stream) {
    const float* xt  = (const float*)d_in[0];
    const float* pw  = (const float*)d_in[1];
    const float* pb  = (const float*)d_in[2];
    const float* swr = (const float*)d_in[3];
    const float* swi = (const float*)d_in[4];
    const float* pww = (const float*)d_in[5];
    const float* pwb = (const float*)d_in[6];
    const float* q1w = (const float*)d_in[7];
    const float* q1b = (const float*)d_in[8];
    const float* q2w = (const float*)d_in[9];
    const float* q2b = (const float*)d_in[10];
    float* out = (float*)d_out;

    float*  X  = (float*)d_ws;
    float2* T1 = (float2*)(X + 33554432);
    float2* T2 = (float2*)((float*)T1 + 16777216);
    float2* T3 = (float2*)((float*)T2 + 4194304);
    float2* T4 = (float2*)((float*)T3 + 1048576);

    k_lift<<<4096, 256, 0, stream>>>(xt, pw, pb, X, T1);
    for (int l = 0; l < 4; ++l) {
        k_xdft<<<8192, 256, 0, stream>>>(T1, T2);
        k_ydft<<<4096, 128, 0, stream>>>(T2, T3);
        k_mix2<<<256, 256, 0, stream>>>(T3, swr, swi, T4, l);
        k_invy<<<4096, 256, 0, stream>>>(T4, T2);
        k_invx<<<16384, 256, 0, stream>>>(T2, T1);
        if (l < 3)
            k_fuse2<<<2048, 256, 0, stream>>>(X, T1, pww, pwb, T1, l);
        else
            k_fuse2_last<<<2048, 256, 0, stream>>>(X, T1, pww, pwb, q1w, q1b, q2w, q2b, out);
    }
}

// Round 7
// 992.331 us; speedup vs baseline: 1.2781x; 1.2781x over previous
//
#include <hip/hip_runtime.h>
#include <math.h>

// FNO3D: B=8, C=3, H=W=64, T=32, WIDTH=32, modes 8x8x8 (4 corners), 4 layers.
// Round 7: MFMA (16x16x32 bf16, fp32 via hi/lo 3-term split) for the pointwise
// 32x32 conv and the q1/q2 head. Spec irfft-t E/O-shared epilogue, fast erf,
// scalar fp32 Goertzel t-DFT. Block = 8 sp x 32 t = 256 pts = 4 waves.
//
// ws floats: X 33,554,432 | T1 16,777,216 | T2 4,194,304 | T3 1,048,576 | T4 1,048,576

#define TWO_PI 6.2831853071795864769f

typedef short bf16x8 __attribute__((ext_vector_type(8)));
typedef float f32x4 __attribute__((ext_vector_type(4)));

__device__ __forceinline__ f32x4 mfma16(bf16x8 a, bf16x8 b, f32x4 c) {
    return __builtin_amdgcn_mfma_f32_16x16x32_bf16(a, b, c, 0, 0, 0);
}

// split 8 consecutive floats into bf16 hi (truncate) + bf16 lo (residual)
__device__ __forceinline__ void split8(float4 a, float4 b, bf16x8& h, bf16x8& l) {
    float f[8] = {a.x, a.y, a.z, a.w, b.x, b.y, b.z, b.w};
    #pragma unroll
    for (int i = 0; i < 8; ++i) {
        unsigned u = __float_as_uint(f[i]);
        h[i] = (short)(u >> 16);
        float hf = __uint_as_float(u & 0xFFFF0000u);
        float lf = f[i] - hf;
        l[i] = (short)(__float_as_uint(lf) >> 16);
    }
}

__device__ __forceinline__ float gelu_fast(float v) {
    float u = v * 0.70710678118654752f;
    float a = fabsf(u);
    float t = __builtin_amdgcn_rcpf(fmaf(0.3275911f, a, 1.0f));
    float p = t * (0.254829592f + t * (-0.284496736f + t * (1.421413741f +
              t * (-1.453152027f + t * 1.061405429f))));
    float e = __expf(-u * u);
    float m = fmaf(-p, e, 1.0f);
    return 0.5f * v * (1.0f + copysignf(m, u));
}

#define GOERTZEL_CONSTS \
    const float C2[8] = {2.0f, 1.9615705608f, 1.8477590650f, 1.6629392246f, \
                         1.4142135624f, 1.1111404660f, 0.7653668647f, 0.3901806440f}; \
    const float CK[8] = {1.0f, 0.9807852804f, 0.9238795325f, 0.8314696123f, \
                         0.7071067812f, 0.5555702330f, 0.3826834324f, 0.1950903220f}; \
    const float SK[8] = {0.0f, 0.1950903220f, 0.3826834324f, 0.5555702330f, \
                         0.7071067812f, 0.8314696123f, 0.9238795325f, 0.9807852804f};

// doubled twiddles e^{+j 2pi k t/32}: ck2=2cos, sk2=2sin
#define MAKE_TWIDDLES(t) \
    float ck2[8], sk2[8]; \
    float c1, s1v; sincosf((t) * (TWO_PI / 32.0f), &s1v, &c1); \
    ck2[1] = 2.0f * c1; sk2[1] = 2.0f * s1v; \
    _Pragma("unroll") \
    for (int k = 2; k < 8; ++k) { \
        float nc = ck2[k-1] * c1 - sk2[k-1] * s1v; \
        float ns = sk2[k-1] * c1 + ck2[k-1] * s1v; \
        ck2[k] = nc; sk2[k] = ns; \
    }

// ---- lift: x_t + grid -> p conv -> X [b][sp][t][c]; fused Goertzel -> T1 ----
__global__ __launch_bounds__(256) void k_lift(const float* __restrict__ xt,
                                              const float* __restrict__ pw,
                                              const float* __restrict__ pb,
                                              float* __restrict__ X,
                                              float2* __restrict__ T1) {
    __shared__ float xs[8448];          // [spl8][t32] rows of 33
    int g = blockIdx.x;                 // b*512 + spt ; 4096 blocks
    int spt = g & 511, b = g >> 9;
    int sp0 = spt * 8;
    int y = sp0 >> 6, x0 = sp0 & 63;
    int tid = threadIdx.x;
    int t = tid & 31, spl = tid >> 5;
    int sp = sp0 + spl;
    float a0 = xt[(b * 3 + 0) * 4096 + sp];
    float a1 = xt[(b * 3 + 1) * 4096 + sp];
    float a2 = xt[(b * 3 + 2) * 4096 + sp];
    float gy = y * (1.0f / 63.0f), gx = (x0 + spl) * (1.0f / 63.0f), gt = t * (1.0f / 31.0f);
    float v[32];
    #pragma unroll
    for (int c = 0; c < 32; ++c) {
        const float* w = pw + c * 6;
        v[c] = pb[c] + w[0] * a0 + w[1] * a1 + w[2] * a2
             + w[3] * gy + w[4] * gx + w[5] * gt;
    }
    float* xg = X + (((long)(b * 4096 + sp)) * 32 + t) * 32;
    #pragma unroll
    for (int j = 0; j < 8; ++j)
        ((float4*)xg)[j] = make_float4(v[4*j], v[4*j+1], v[4*j+2], v[4*j+3]);
    float* row = xs + (spl * 32 + t) * 33;
    #pragma unroll
    for (int c = 0; c < 32; ++c) row[c] = v[c];
    __syncthreads();
    int c = tid & 31, sl = tid >> 5;
    GOERTZEL_CONSTS
    float s1[8], s2[8];
    #pragma unroll
    for (int k = 0; k < 8; ++k) { s1[k] = 0.f; s2[k] = 0.f; }
    const float* col = xs + (sl * 32) * 33 + c;
    for (int tt = 0; tt < 32; ++tt) {
        float xv = col[tt * 33];
        #pragma unroll
        for (int k = 0; k < 8; ++k) {
            float s0 = xv + C2[k] * s1[k] - s2[k];
            s2[k] = s1[k]; s1[k] = s0;
        }
    }
    float2* ob = T1 + ((long)(b * 32 + c) * 4096 + sp0 + sl) * 8;
    #pragma unroll
    for (int k = 0; k < 8; ++k)
        ob[k] = make_float2(CK[k] * s1[k] - s2[k], SK[k] * s1[k]);
}

// ---------------- forward x-DFT: T1 -> T2 (16 modes) ----------------
__global__ __launch_bounds__(256) void k_xdft(const float2* __restrict__ T1, float2* __restrict__ T2) {
    __shared__ float2 s[1024];
    __shared__ float2 tw[64];
    int g = blockIdx.x;              // bc*32 + ypair ; 8192 blocks
    int ypair = g & 31; int bc = g >> 5;
    long base = ((long)bc * 64 + ypair * 2) * 512;
    int tid = threadIdx.x;
    for (int k = tid; k < 1024; k += 256) s[k] = T1[base + k];
    if (tid < 64) { float sn, cs; sincosf(tid * (TWO_PI / 64.0f), &sn, &cs); tw[tid] = make_float2(cs, sn); }
    __syncthreads();
    int half = tid >> 7, jj = tid & 127;
    int kxi = jj >> 3, kt = jj & 7;
    int kx = kxi < 8 ? kxi : kxi + 48;
    const float2* row = s + half * 512;
    float sr = 0.f, si = 0.f;
    for (int x = 0; x < 64; ++x) {
        float2 w = tw[(kx * x) & 63];
        float2 a = row[x * 8 + kt];
        sr += a.x * w.x + a.y * w.y;
        si += a.y * w.x - a.x * w.y;
    }
    T2[((long)bc * 64 + ypair * 2 + half) * 128 + jj] = make_float2(sr, si);
}

// ---------------- forward y-DFT: T2 -> T3 (16 modes) ----------------
__global__ __launch_bounds__(128) void k_ydft(const float2* __restrict__ T2, float2* __restrict__ T3) {
    __shared__ float2 s[512];
    __shared__ float2 tw[64];
    int g = blockIdx.x;              // bc*16 + kx ; 4096 blocks
    int kx = g & 15; int bc = g >> 4;
    int tid = threadIdx.x;
    for (int k = tid; k < 512; k += 128) {
        int y = k >> 3, kt = k & 7;
        s[k] = T2[((long)bc * 64 + y) * 128 + kx * 8 + kt];
    }
    if (tid < 64) { float sn, cs; sincosf(tid * (TWO_PI / 64.0f), &sn, &cs); tw[tid] = make_float2(cs, sn); }
    __syncthreads();
    int kyi = tid >> 3, kt = tid & 7;
    int ky = kyi < 8 ? kyi : kyi + 48;
    float sr = 0.f, si = 0.f;
    for (int y = 0; y < 64; ++y) {
        float2 w = tw[(ky * y) & 63];
        float2 a = s[y * 8 + kt];
        sr += a.x * w.x + a.y * w.y;
        si += a.y * w.x - a.x * w.y;
    }
    T3[((long)bc * 256 + kyi * 16 + kx) * 8 + kt] = make_float2(sr, si);
}

// -------- mode mix (mode-major, b-loop amortizes weight reads) --------
__global__ __launch_bounds__(256) void k_mix2(const float2* __restrict__ T3,
                                              const float* __restrict__ wr,
                                              const float* __restrict__ wi,
                                              float2* __restrict__ T4, int layer) {
    __shared__ float2 s[2304];
    int mode = blockIdx.x;           // 256 blocks
    int kyi = mode >> 4, kxi = mode & 15;
    int tid = threadIdx.x;
    {
        int bb = tid >> 5, i = tid & 31;
        const float2* src = T3 + ((long)(bb * 32 + i) * 256 + mode) * 8;
        float2* dst = s + (i * 8 + bb) * 9;
        #pragma unroll
        for (int k = 0; k < 8; ++k) dst[k] = src[k];
    }
    __syncthreads();
    int corner = (kyi >= 8 ? 1 : 0) + (kxi >= 8 ? 2 : 0);
    long wbase = (long)(layer * 4 + corner) * 524288 + (long)(kyi & 7) * 64 + (long)(kxi & 7) * 8;
    int o = tid >> 3, kt = tid & 7;
    long wb = wbase + (long)o * 512 + kt;
    float2 acc[8];
    #pragma unroll
    for (int bb = 0; bb < 8; ++bb) acc[bb] = make_float2(0.f, 0.f);
    for (int i = 0; i < 32; ++i) {
        float r = wr[wb + (long)i * 16384], im = wi[wb + (long)i * 16384];
        #pragma unroll
        for (int bb = 0; bb < 8; ++bb) {
            float2 a = s[(i * 8 + bb) * 9 + kt];
            acc[bb].x += a.x * r - a.y * im;
            acc[bb].y += a.x * im + a.y * r;
        }
    }
    #pragma unroll
    for (int bb = 0; bb < 8; ++bb)
        T4[((long)(bb * 32 + o) * 256 + mode) * 8 + kt] = acc[bb];
}

// ---------------- inverse y: T4 -> T2 space ----------------
__global__ __launch_bounds__(256) void k_invy(const float2* __restrict__ T4, float2* __restrict__ T5) {
    __shared__ float2 s[128];
    __shared__ float2 tw[64];
    int g = blockIdx.x;              // bc*16 + kx ; 4096 blocks
    int kx = g & 15; int bc = g >> 4;
    int tid = threadIdx.x;
    if (tid < 128) {
        int kyi = tid >> 3, kt = tid & 7;
        s[tid] = T4[((long)bc * 256 + kyi * 16 + kx) * 8 + kt];
    } else if (tid < 192) {
        int m = tid - 128; float sn, cs; sincosf(m * (TWO_PI / 64.0f), &sn, &cs); tw[m] = make_float2(cs, sn);
    }
    __syncthreads();
    for (int r = 0; r < 2; ++r) {
        int j = tid + r * 256;
        int y = j >> 3, kt = j & 7;
        float sr = 0.f, si = 0.f;
        for (int kyi = 0; kyi < 16; ++kyi) {
            int ky = kyi < 8 ? kyi : kyi + 48;
            float2 w = tw[(ky * y) & 63];
            float2 a = s[kyi * 8 + kt];
            sr += a.x * w.x - a.y * w.y;
            si += a.y * w.x + a.x * w.y;
        }
        T5[((long)bc * 64 + y) * 128 + kx * 8 + kt] = make_float2(sr, si);
    }
}

// ---------------- inverse x: T2 space -> T1 space (T6) ----------------
__global__ __launch_bounds__(256) void k_invx(const float2* __restrict__ T5, float2* __restrict__ T6) {
    __shared__ float2 s[128];
    __shared__ float2 tw[64];
    int g = blockIdx.x;              // bc*64 + y ; 16384 blocks
    int tid = threadIdx.x;
    if (tid < 128) {
        s[tid] = T5[(long)g * 128 + tid];
    } else if (tid < 192) {
        int m = tid - 128; float sn, cs; sincosf(m * (TWO_PI / 64.0f), &sn, &cs); tw[m] = make_float2(cs, sn);
    }
    __syncthreads();
    for (int r = 0; r < 2; ++r) {
        int j = tid + r * 256;
        int x = j >> 3, kt = j & 7;
        float sr = 0.f, si = 0.f;
        for (int kxi = 0; kxi < 16; ++kxi) {
            int kx = kxi < 8 ? kxi : kxi + 48;
            float2 w = tw[(kx * x) & 63];
            float2 a = s[kxi * 8 + kt];
            sr += a.x * w.x - a.y * w.y;
            si += a.y * w.x + a.x * w.y;
        }
        T6[(long)g * 512 + j] = make_float2(sr, si);
    }
}

// ---- fuse3: MFMA pointwise + E/O spec + gelu; X update; Goertzel -> T1 ----
__global__ __launch_bounds__(256) void k_fuse3(float* __restrict__ X, const float2* __restrict__ T6,
                                               const float* __restrict__ pww,
                                               const float* __restrict__ pwb,
                                               float2* __restrict__ T1, int layer) {
    __shared__ float smem[9216];     // ts 4096 f (first) / xs 256 rows x 36
    float2* ts = (float2*)smem;
    int g = blockIdx.x;              // b*512 + spt ; 4096 blocks
    int spt = g & 511, b = g >> 9;
    int sp0 = spt * 8;
    int tid = threadIdx.x;
    {   // stage spectral tile pre-scaled: ts[(o*8+spl)*8 + kt]
        int o = tid >> 3, spl = tid & 7;
        const float4* src = (const float4*)(T6 + ((long)(b * 32 + o) * 4096 + sp0 + spl) * 8);
        float4* dst = (float4*)(ts + (o * 8 + spl) * 8);
        const float S = 1.0f / 131072.0f;
        #pragma unroll
        for (int j = 0; j < 4; ++j) {
            float4 q = src[j];
            dst[j] = make_float4(q.x * S, q.y * S, q.z * S, q.w * S);
        }
    }
    int wave = tid >> 6, lane = tid & 63, l15 = lane & 15, quad = lane >> 4;
    int wb = wave * 64;
    const float* wl = pww + layer * 1024;
    const float* bl = pwb + layer * 32;
    bf16x8 wah[2], wal[2];
    f32x4 acc[2][4];
    #pragma unroll
    for (int mt = 0; mt < 2; ++mt) {
        const float4* p = (const float4*)(wl + (mt * 16 + l15) * 32 + quad * 8);
        split8(p[0], p[1], wah[mt], wal[mt]);
        float4 bv = *(const float4*)(bl + mt * 16 + quad * 4);
        f32x4 bi; bi[0] = bv.x; bi[1] = bv.y; bi[2] = bv.z; bi[3] = bv.w;
        #pragma unroll
        for (int nt = 0; nt < 4; ++nt) acc[mt][nt] = bi;
    }
    #pragma unroll
    for (int nt = 0; nt < 4; ++nt) {
        int pt = wb + nt * 16 + l15;
        int spl = pt >> 5, t = pt & 31;
        const float4* xp = (const float4*)(X + (((long)(b * 4096 + sp0 + spl)) * 32 + t) * 32 + quad * 8);
        bf16x8 bh, blo; split8(xp[0], xp[1], bh, blo);
        #pragma unroll
        for (int mt = 0; mt < 2; ++mt) {
            acc[mt][nt] = mfma16(wah[mt], bh, acc[mt][nt]);
            acc[mt][nt] = mfma16(wal[mt], bh, acc[mt][nt]);
            acc[mt][nt] = mfma16(wah[mt], blo, acc[mt][nt]);
        }
    }
    __syncthreads();                 // ts fully staged
    MAKE_TWIDDLES(l15)
    #pragma unroll
    for (int mt = 0; mt < 2; ++mt)
        #pragma unroll
        for (int reg = 0; reg < 4; ++reg) {
            int o = mt * 16 + quad * 4 + reg;
            #pragma unroll
            for (int sph = 0; sph < 2; ++sph) {
                const float4* f4 = (const float4*)(ts + (o * 8 + 2 * wave + sph) * 8);
                float4 q0 = f4[0], q1f = f4[1], q2f = f4[2], q3f = f4[3];
                float E = q0.x + q1f.x * ck2[2] - q1f.y * sk2[2]
                        + q2f.x * ck2[4] - q2f.y * sk2[4]
                        + q3f.x * ck2[6] - q3f.y * sk2[6];
                float O = q0.z * ck2[1] - q0.w * sk2[1]
                        + q1f.z * ck2[3] - q1f.w * sk2[3]
                        + q2f.z * ck2[5] - q2f.w * sk2[5]
                        + q3f.z * ck2[7] - q3f.w * sk2[7];
                acc[mt][sph * 2 + 0][reg] = gelu_fast(acc[mt][sph * 2 + 0][reg] + E + O);
                acc[mt][sph * 2 + 1][reg] = gelu_fast(acc[mt][sph * 2 + 1][reg] + E - O);
            }
        }
    __syncthreads();                 // ts reads done; smem becomes xs
    #pragma unroll
    for (int mt = 0; mt < 2; ++mt)
        #pragma unroll
        for (int nt = 0; nt < 4; ++nt) {
            int pt = wb + nt * 16 + l15;
            int spl = pt >> 5, t = pt & 31;
            int o0 = mt * 16 + quad * 4;
            float4 w4 = make_float4(acc[mt][nt][0], acc[mt][nt][1], acc[mt][nt][2], acc[mt][nt][3]);
            *(float4*)(X + (((long)(b * 4096 + sp0 + spl)) * 32 + t) * 32 + o0) = w4;
            *(float4*)(smem + (spl * 32 + t) * 36 + o0) = w4;
        }
    __syncthreads();
    // Goertzel t-DFT for next layer
    int c = tid & 31, sl = tid >> 5;
    GOERTZEL_CONSTS
    float s1[8], s2[8];
    #pragma unroll
    for (int k = 0; k < 8; ++k) { s1[k] = 0.f; s2[k] = 0.f; }
    const float* col = smem + (sl * 32) * 36 + c;
    for (int tt = 0; tt < 32; ++tt) {
        float xv = col[tt * 36];
        #pragma unroll
        for (int k = 0; k < 8; ++k) {
            float s0 = xv + C2[k] * s1[k] - s2[k];
            s2[k] = s1[k]; s1[k] = s0;
        }
    }
    float2* ob = T1 + ((long)(b * 32 + c) * 4096 + sp0 + sl) * 8;
    #pragma unroll
    for (int k = 0; k < 8; ++k)
        ob[k] = make_float2(CK[k] * s1[k] - s2[k], SK[k] * s1[k]);
}

// ---- fuse3_last: MFMA layer-3 pointwise + MFMA q1 head + VALU q2 -> out ----
__global__ __launch_bounds__(256) void k_fuse3_last(const float* __restrict__ X, const float2* __restrict__ T6,
                                                    const float* __restrict__ pww, const float* __restrict__ pwb,
                                                    const float* __restrict__ q1w, const float* __restrict__ q1b,
                                                    const float* __restrict__ q2w, const float* __restrict__ q2b,
                                                    float* __restrict__ out) {
    __shared__ float smem[9408];     // ts 4096 / acts 256x36 (union); q2w at 9216
    float2* ts = (float2*)smem;
    int g = blockIdx.x;              // b*512 + spt ; 4096 blocks
    int spt = g & 511, b = g >> 9;
    int sp0 = spt * 8;
    int tid = threadIdx.x;
    {
        int o = tid >> 3, spl = tid & 7;
        const float4* src = (const float4*)(T6 + ((long)(b * 32 + o) * 4096 + sp0 + spl) * 8);
        float4* dst = (float4*)(ts + (o * 8 + spl) * 8);
        const float S = 1.0f / 131072.0f;
        #pragma unroll
        for (int j = 0; j < 4; ++j) {
            float4 q = src[j];
            dst[j] = make_float4(q.x * S, q.y * S, q.z * S, q.w * S);
        }
    }
    if (tid < 192) smem[9216 + tid] = q2w[tid];
    int wave = tid >> 6, lane = tid & 63, l15 = lane & 15, quad = lane >> 4;
    int wb = wave * 64;
    const float* wl = pww + 3 * 1024;
    const float* bl = pwb + 3 * 32;
    bf16x8 wah[2], wal[2];
    f32x4 acc[2][4];
    #pragma unroll
    for (int mt = 0; mt < 2; ++mt) {
        const float4* p = (const float4*)(wl + (mt * 16 + l15) * 32 + quad * 8);
        split8(p[0], p[1], wah[mt], wal[mt]);
        float4 bv = *(const float4*)(bl + mt * 16 + quad * 4);
        f32x4 bi; bi[0] = bv.x; bi[1] = bv.y; bi[2] = bv.z; bi[3] = bv.w;
        #pragma unroll
        for (int nt = 0; nt < 4; ++nt) acc[mt][nt] = bi;
    }
    #pragma unroll
    for (int nt = 0; nt < 4; ++nt) {
        int pt = wb + nt * 16 + l15;
        int spl = pt >> 5, t = pt & 31;
        const float4* xp = (const float4*)(X + (((long)(b * 4096 + sp0 + spl)) * 32 + t) * 32 + quad * 8);
        bf16x8 bh, blo; split8(xp[0], xp[1], bh, blo);
        #pragma unroll
        for (int mt = 0; mt < 2; ++mt) {
            acc[mt][nt] = mfma16(wah[mt], bh, acc[mt][nt]);
            acc[mt][nt] = mfma16(wal[mt], bh, acc[mt][nt]);
            acc[mt][nt] = mfma16(wah[mt], blo, acc[mt][nt]);
        }
    }
    __syncthreads();
    MAKE_TWIDDLES(l15)
    #pragma unroll
    for (int mt = 0; mt < 2; ++mt)
        #pragma unroll
        for (int reg = 0; reg < 4; ++reg) {
            int o = mt * 16 + quad * 4 + reg;
            #pragma unroll
            for (int sph = 0; sph < 2; ++sph) {
                const float4* f4 = (const float4*)(ts + (o * 8 + 2 * wave + sph) * 8);
                float4 q0 = f4[0], q1f = f4[1], q2f = f4[2], q3f = f4[3];
                float E = q0.x + q1f.x * ck2[2] - q1f.y * sk2[2]
                        + q2f.x * ck2[4] - q2f.y * sk2[4]
                        + q3f.x * ck2[6] - q3f.y * sk2[6];
                float O = q0.z * ck2[1] - q0.w * sk2[1]
                        + q1f.z * ck2[3] - q1f.w * sk2[3]
                        + q2f.z * ck2[5] - q2f.w * sk2[5]
                        + q3f.z * ck2[7] - q3f.w * sk2[7];
                acc[mt][sph * 2 + 0][reg] = gelu_fast(acc[mt][sph * 2 + 0][reg] + E + O);
                acc[mt][sph * 2 + 1][reg] = gelu_fast(acc[mt][sph * 2 + 1][reg] + E - O);
            }
        }
    __syncthreads();                 // ts reads done; smem[0..9215] becomes acts[pt][36]
    #pragma unroll
    for (int mt = 0; mt < 2; ++mt)
        #pragma unroll
        for (int nt = 0; nt < 4; ++nt) {
            int pt = wb + nt * 16 + l15;
            int o0 = mt * 16 + quad * 4;
            *(float4*)(smem + pt * 36 + o0) =
                make_float4(acc[mt][nt][0], acc[mt][nt][1], acc[mt][nt][2], acc[mt][nt][3]);
        }
    __syncthreads();
    // head: q1 (MFMA) + gelu + q2 (lane-local + shfl reduce)
    bf16x8 qah[4], qal[4];
    f32x4 qbv[4];
    #pragma unroll
    for (int mt = 0; mt < 4; ++mt) {
        const float4* p = (const float4*)(q1w + (mt * 16 + l15) * 32 + quad * 8);
        split8(p[0], p[1], qah[mt], qal[mt]);
        float4 bv = *(const float4*)(q1b + mt * 16 + quad * 4);
        qbv[mt][0] = bv.x; qbv[mt][1] = bv.y; qbv[mt][2] = bv.z; qbv[mt][3] = bv.w;
    }
    const float* q2l = smem + 9216;
    float q2b0 = q2b[0], q2b1 = q2b[1], q2b2 = q2b[2];
    float oc0[4], oc1[4], oc2[4];
    #pragma unroll
    for (int nt = 0; nt < 4; ++nt) {
        int pt = wb + nt * 16 + l15;
        const float4* bp = (const float4*)(smem + pt * 36 + quad * 8);
        bf16x8 bh, blo; split8(bp[0], bp[1], bh, blo);
        float p0 = 0.f, p1 = 0.f, p2 = 0.f;
        #pragma unroll
        for (int mt = 0; mt < 4; ++mt) {
            f32x4 h = qbv[mt];
            h = mfma16(qah[mt], bh, h);
            h = mfma16(qal[mt], bh, h);
            h = mfma16(qah[mt], blo, h);
            #pragma unroll
            for (int reg = 0; reg < 4; ++reg) {
                float a1 = gelu_fast(h[reg]);
                int hh = mt * 16 + quad * 4 + reg;
                p0 += q2l[hh] * a1;
                p1 += q2l[64 + hh] * a1;
                p2 += q2l[128 + hh] * a1;
            }
        }
        p0 += __shfl_xor(p0, 16); p0 += __shfl_xor(p0, 32);
        p1 += __shfl_xor(p1, 16); p1 += __shfl_xor(p1, 32);
        p2 += __shfl_xor(p2, 16); p2 += __shfl_xor(p2, 32);
        oc0[nt] = p0 + q2b0; oc1[nt] = p1 + q2b1; oc2[nt] = p2 + q2b2;
    }
    __syncthreads();                 // act reads done; smem[0..863] becomes out-stage
    if (quad == 0) {
        #pragma unroll
        for (int nt = 0; nt < 4; ++nt) {
            int pt = wb + nt * 16 + l15;
            int spl = pt >> 5, t = pt & 31;
            smem[(t * 3 + 0) * 9 + spl] = oc0[nt];
            smem[(t * 3 + 1) * 9 + spl] = oc1[nt];
            smem[(t * 3 + 2) * 9 + spl] = oc2[nt];
        }
    }
    __syncthreads();
    for (int m = tid; m < 768; m += 256) {
        int u = m >> 3, spl = m & 7;
        out[((long)(b * 96 + u)) * 4096 + sp0 + spl] = smem[u * 9 + spl];
    }
}

extern "C" void kernel_launch(void* const* d_in, const int* in_sizes, int n_in,
                              void* d_out, int out_size, void* d_ws, size_t ws_size,
                              hipStream_t stream) {
    const float* xt  = (const float*)d_in[0];
    const float* pw  = (const float*)d_in[1];
    const float* pb  = (const float*)d_in[2];
    const float* swr = (const float*)d_in[3];
    const float* swi = (const float*)d_in[4];
    const float* pww = (const float*)d_in[5];
    const float* pwb = (const float*)d_in[6];
    const float* q1w = (const float*)d_in[7];
    const float* q1b = (const float*)d_in[8];
    const float* q2w = (const float*)d_in[9];
    const float* q2b = (const float*)d_in[10];
    float* out = (float*)d_out;

    float*  X  = (float*)d_ws;
    float2* T1 = (float2*)(X + 33554432);
    float2* T2 = (float2*)((float*)T1 + 16777216);
    float2* T3 = (float2*)((float*)T2 + 4194304);
    float2* T4 = (float2*)((float*)T3 + 1048576);

    k_lift<<<4096, 256, 0, stream>>>(xt, pw, pb, X, T1);
    for (int l = 0; l < 4; ++l) {
        k_xdft<<<8192, 256, 0, stream>>>(T1, T2);
        k_ydft<<<4096, 128, 0, stream>>>(T2, T3);
        k_mix2<<<256, 256, 0, stream>>>(T3, swr, swi, T4, l);
        k_invy<<<4096, 256, 0, stream>>>(T4, T2);
        k_invx<<<16384, 256, 0, stream>>>(T2, T1);
        if (l < 3)
            k_fuse3<<<4096, 256, 0, stream>>>(X, T1, pww, pwb, T1, l);
        else
            k_fuse3_last<<<4096, 256, 0, stream>>>(X, T1, pww, pwb, q1w, q1b, q2w, q2b, out);
    }
}

// Round 8
// 816.397 us; speedup vs baseline: 1.5535x; 1.2155x over previous
//
#include <hip/hip_runtime.h>
#include <math.h>

// FNO3D: B=8, C=3, H=W=64, T=32, WIDTH=32, modes 8x8x8 (4 corners), 4 layers.
// Round 8: algebraic halving everywhere.
//  - E/O radix-2 Goertzel t-DFT (lift, fuse3): 16-sample recurrences, sign=(-1)^k
//  - E/O split in xdft/ydft (parity of kx/ky), P/M mode pairing in invy/invx
//  - ts rows padded to 66 f2 (2-way bank aliasing only), packed gelu2, __sincosf
//
// ws floats: X 33,554,432 | T1 16,777,216 | T2 4,194,304 | T3 1,048,576 | T4 1,048,576

#define TWO_PI 6.2831853071795864769f

typedef short bf16x8 __attribute__((ext_vector_type(8)));
typedef float f32x4 __attribute__((ext_vector_type(4)));
typedef float v2f __attribute__((ext_vector_type(2)));

__device__ __forceinline__ f32x4 mfma16(bf16x8 a, bf16x8 b, f32x4 c) {
    return __builtin_amdgcn_mfma_f32_16x16x32_bf16(a, b, c, 0, 0, 0);
}

__device__ __forceinline__ void split8(float4 a, float4 b, bf16x8& h, bf16x8& l) {
    float f[8] = {a.x, a.y, a.z, a.w, b.x, b.y, b.z, b.w};
    #pragma unroll
    for (int i = 0; i < 8; ++i) {
        unsigned u = __float_as_uint(f[i]);
        h[i] = (short)(u >> 16);
        float hf = __uint_as_float(u & 0xFFFF0000u);
        float lf = f[i] - hf;
        l[i] = (short)(__float_as_uint(lf) >> 16);
    }
}

__device__ __forceinline__ v2f make2(float x) { v2f r; r.x = x; r.y = x; return r; }
__device__ __forceinline__ v2f fma2(v2f a, v2f b, v2f c) { return __builtin_elementwise_fma(a, b, c); }

// packed gelu via A&S 7.1.26 erf (|err|<=1.5e-7)
__device__ __forceinline__ v2f gelu2(v2f v) {
    v2f u = v * 0.70710678118654752f;
    v2f a = __builtin_elementwise_abs(u);
    v2f den = fma2(a, make2(0.3275911f), make2(1.0f));
    v2f t; t.x = __builtin_amdgcn_rcpf(den.x); t.y = __builtin_amdgcn_rcpf(den.y);
    v2f p = t * (0.254829592f + t * (-0.284496736f + t * (1.421413741f +
            t * (-1.453152027f + t * 1.061405429f))));
    v2f e; e.x = __expf(-u.x * u.x); e.y = __expf(-u.y * u.y);
    v2f m = fma2(-p, e, make2(1.0f));
    v2f erfu = __builtin_elementwise_copysign(m, u);
    return 0.5f * v * (1.0f + erfu);
}

__device__ __forceinline__ void gelu4(f32x4& q) {
    v2f p0; p0.x = q[0]; p0.y = q[1];
    v2f p1; p1.x = q[2]; p1.y = q[3];
    p0 = gelu2(p0); p1 = gelu2(p1);
    q[0] = p0.x; q[1] = p0.y; q[2] = p1.x; q[3] = p1.y;
}

#define GOERTZEL_CONSTS \
    const float C2[8] = {2.0f, 1.9615705608f, 1.8477590650f, 1.6629392246f, \
                         1.4142135624f, 1.1111404660f, 0.7653668647f, 0.3901806440f}; \
    const float CK[8] = {1.0f, 0.9807852804f, 0.9238795325f, 0.8314696123f, \
                         0.7071067812f, 0.5555702330f, 0.3826834324f, 0.1950903220f}; \
    const float SK[8] = {0.0f, 0.1950903220f, 0.3826834324f, 0.5555702330f, \
                         0.7071067812f, 0.8314696123f, 0.9238795325f, 0.9807852804f};

// E/O 16-sample Goertzel over a strided LDS column; emit X_k = (-1)^k (CK s1 - s2, SK s1)
#define GOERTZEL_EO(col, STRIDE, emit_ptr) { \
    GOERTZEL_CONSTS \
    float s1[8], s2[8]; \
    _Pragma("unroll") \
    for (int k = 0; k < 8; ++k) { s1[k] = 0.f; s2[k] = 0.f; } \
    for (int tt = 0; tt < 16; ++tt) { \
        float x0 = (col)[tt * (STRIDE)], x1 = (col)[(tt + 16) * (STRIDE)]; \
        float ev = x0 + x1, ov = x0 - x1; \
        _Pragma("unroll") \
        for (int k = 0; k < 8; ++k) { \
            float v = (k & 1) ? ov : ev; \
            float s0 = v + C2[k] * s1[k] - s2[k]; \
            s2[k] = s1[k]; s1[k] = s0; \
        } \
    } \
    _Pragma("unroll") \
    for (int k = 0; k < 8; ++k) { \
        float R = CK[k] * s1[k] - s2[k]; \
        float I = SK[k] * s1[k]; \
        if (k & 1) { R = -R; I = -I; } \
        (emit_ptr)[k] = make_float2(R, I); \
    } }

// doubled twiddles e^{+j 2pi k t/32}: ck2=2cos, sk2=2sin
#define MAKE_TWIDDLES(t) \
    float ck2[8], sk2[8]; \
    float c1, s1v; __sincosf((t) * (TWO_PI / 32.0f), &s1v, &c1); \
    ck2[1] = 2.0f * c1; sk2[1] = 2.0f * s1v; \
    _Pragma("unroll") \
    for (int k = 2; k < 8; ++k) { \
        float nc = ck2[k-1] * c1 - sk2[k-1] * s1v; \
        float ns = sk2[k-1] * c1 + ck2[k-1] * s1v; \
        ck2[k] = nc; sk2[k] = ns; \
    }

// ---- lift: x_t + grid -> p conv -> X [b][sp][t][c]; fused E/O Goertzel -> T1 ----
__global__ __launch_bounds__(256) void k_lift(const float* __restrict__ xt,
                                              const float* __restrict__ pw,
                                              const float* __restrict__ pb,
                                              float* __restrict__ X,
                                              float2* __restrict__ T1) {
    __shared__ float xs[8448];          // [spl8][t32] rows of 33
    int g = blockIdx.x;                 // b*512 + spt ; 4096 blocks
    int spt = g & 511, b = g >> 9;
    int sp0 = spt * 8;
    int y = sp0 >> 6, x0 = sp0 & 63;
    int tid = threadIdx.x;
    int t = tid & 31, spl = tid >> 5;
    int sp = sp0 + spl;
    float a0 = xt[(b * 3 + 0) * 4096 + sp];
    float a1 = xt[(b * 3 + 1) * 4096 + sp];
    float a2 = xt[(b * 3 + 2) * 4096 + sp];
    float gy = y * (1.0f / 63.0f), gx = (x0 + spl) * (1.0f / 63.0f), gt = t * (1.0f / 31.0f);
    float v[32];
    #pragma unroll
    for (int c = 0; c < 32; ++c) {
        const float* w = pw + c * 6;
        v[c] = pb[c] + w[0] * a0 + w[1] * a1 + w[2] * a2
             + w[3] * gy + w[4] * gx + w[5] * gt;
    }
    float* xg = X + (((long)(b * 4096 + sp)) * 32 + t) * 32;
    #pragma unroll
    for (int j = 0; j < 8; ++j)
        ((float4*)xg)[j] = make_float4(v[4*j], v[4*j+1], v[4*j+2], v[4*j+3]);
    float* row = xs + (spl * 32 + t) * 33;
    #pragma unroll
    for (int c = 0; c < 32; ++c) row[c] = v[c];
    __syncthreads();
    int c = tid & 31, sl = tid >> 5;
    const float* col = xs + (sl * 32) * 33 + c;
    float2* ob = T1 + ((long)(b * 32 + c) * 4096 + sp0 + sl) * 8;
    GOERTZEL_EO(col, 33, ob)
}

// ------- forward x-DFT (E/O split): T1 -> T2 (16 modes) -------
__global__ __launch_bounds__(256) void k_xdft(const float2* __restrict__ T1, float2* __restrict__ T2) {
    __shared__ float2 s[1024];
    __shared__ float2 tw[64];
    int g = blockIdx.x;              // bc*32 + ypair ; 8192 blocks
    int ypair = g & 31; int bc = g >> 5;
    long base = ((long)bc * 64 + ypair * 2) * 512;
    int tid = threadIdx.x;
    for (int k = tid; k < 1024; k += 256) s[k] = T1[base + k];
    if (tid < 64) { float sn, cs; __sincosf(tid * (TWO_PI / 64.0f), &sn, &cs); tw[tid] = make_float2(cs, sn); }
    __syncthreads();
    // in-place butterfly: x<32 -> E at x, O at x+32 (per half-row)
    #pragma unroll
    for (int r = 0; r < 2; ++r) {
        int j = tid + r * 256;       // 512 pairs: (half, x<32, kt)
        int half = j >> 8, rem = j & 255;
        int idx = half * 512 + rem;
        float2 a = s[idx], b2 = s[idx + 256];
        s[idx] = make_float2(a.x + b2.x, a.y + b2.y);
        s[idx + 256] = make_float2(a.x - b2.x, a.y - b2.y);
    }
    __syncthreads();
    int half = tid >> 7, jj = tid & 127;
    int kxi = jj >> 3, kt = jj & 7;
    int kx = kxi < 8 ? kxi : kxi + 48;
    const float2* row = s + half * 512 + (kx & 1) * 256;
    float sr = 0.f, si = 0.f;
    for (int x = 0; x < 32; ++x) {
        float2 w = tw[(kx * x) & 63];
        float2 a = row[x * 8 + kt];
        sr += a.x * w.x + a.y * w.y;
        si += a.y * w.x - a.x * w.y;
    }
    T2[((long)bc * 64 + ypair * 2 + half) * 128 + jj] = make_float2(sr, si);
}

// ------- forward y-DFT (E/O split): T2 -> T3 (16 modes) -------
__global__ __launch_bounds__(128) void k_ydft(const float2* __restrict__ T2, float2* __restrict__ T3) {
    __shared__ float2 s[512];
    __shared__ float2 tw[64];
    int g = blockIdx.x;              // bc*16 + kx ; 4096 blocks
    int kx = g & 15; int bc = g >> 4;
    int tid = threadIdx.x;
    for (int k = tid; k < 512; k += 128) {
        int y = k >> 3, kt = k & 7;
        s[k] = T2[((long)bc * 64 + y) * 128 + kx * 8 + kt];
    }
    if (tid < 64) { float sn, cs; __sincosf(tid * (TWO_PI / 64.0f), &sn, &cs); tw[tid] = make_float2(cs, sn); }
    __syncthreads();
    #pragma unroll
    for (int r = 0; r < 2; ++r) {
        int j = tid + r * 128;       // 256 pairs: y<32 x kt
        float2 a = s[j], b2 = s[j + 256];
        s[j] = make_float2(a.x + b2.x, a.y + b2.y);
        s[j + 256] = make_float2(a.x - b2.x, a.y - b2.y);
    }
    __syncthreads();
    int kyi = tid >> 3, kt = tid & 7;
    int ky = kyi < 8 ? kyi : kyi + 48;
    const float2* row = s + (ky & 1) * 256;
    float sr = 0.f, si = 0.f;
    for (int y = 0; y < 32; ++y) {
        float2 w = tw[(ky * y) & 63];
        float2 a = row[y * 8 + kt];
        sr += a.x * w.x + a.y * w.y;
        si += a.y * w.x - a.x * w.y;
    }
    T3[((long)bc * 256 + kyi * 16 + kx) * 8 + kt] = make_float2(sr, si);
}

// -------- mode mix (mode-major, b-loop amortizes weight reads) --------
__global__ __launch_bounds__(256) void k_mix2(const float2* __restrict__ T3,
                                              const float* __restrict__ wr,
                                              const float* __restrict__ wi,
                                              float2* __restrict__ T4, int layer) {
    __shared__ float2 s[2304];
    int mode = blockIdx.x;           // 256 blocks
    int kyi = mode >> 4, kxi = mode & 15;
    int tid = threadIdx.x;
    {
        int bb = tid >> 5, i = tid & 31;
        const float2* src = T3 + ((long)(bb * 32 + i) * 256 + mode) * 8;
        float2* dst = s + (i * 8 + bb) * 9;
        #pragma unroll
        for (int k = 0; k < 8; ++k) dst[k] = src[k];
    }
    __syncthreads();
    int corner = (kyi >= 8 ? 1 : 0) + (kxi >= 8 ? 2 : 0);
    long wbase = (long)(layer * 4 + corner) * 524288 + (long)(kyi & 7) * 64 + (long)(kxi & 7) * 8;
    int o = tid >> 3, kt = tid & 7;
    long wb = wbase + (long)o * 512 + kt;
    float2 acc[8];
    #pragma unroll
    for (int bb = 0; bb < 8; ++bb) acc[bb] = make_float2(0.f, 0.f);
    for (int i = 0; i < 32; ++i) {
        float r = wr[wb + (long)i * 16384], im = wi[wb + (long)i * 16384];
        #pragma unroll
        for (int bb = 0; bb < 8; ++bb) {
            float2 a = s[(i * 8 + bb) * 9 + kt];
            acc[bb].x += a.x * r - a.y * im;
            acc[bb].y += a.x * im + a.y * r;
        }
    }
    #pragma unroll
    for (int bb = 0; bb < 8; ++bb)
        T4[((long)(bb * 32 + o) * 256 + mode) * 8 + kt] = acc[bb];
}

// ------- inverse y (P/M pairing): T4 -> T2 space -------
__global__ __launch_bounds__(256) void k_invy(const float2* __restrict__ T4, float2* __restrict__ T5) {
    __shared__ float2 s[128];
    __shared__ float2 tw[64];
    __shared__ float2 pmP[56], pmM[56];   // j=1..7 x kt
    int g = blockIdx.x;              // bc*16 + kx ; 4096 blocks
    int kx = g & 15; int bc = g >> 4;
    int tid = threadIdx.x;
    if (tid < 128) {
        int kyi = tid >> 3, kt = tid & 7;
        s[tid] = T4[((long)bc * 256 + kyi * 16 + kx) * 8 + kt];
    } else if (tid < 192) {
        int m = tid - 128; float sn, cs; __sincosf(m * (TWO_PI / 64.0f), &sn, &cs); tw[m] = make_float2(cs, sn);
    }
    __syncthreads();
    if (tid < 56) {
        int j = (tid >> 3) + 1, kt = tid & 7;
        float2 a = s[j * 8 + kt], b2 = s[(16 - j) * 8 + kt];
        pmP[tid] = make_float2(a.x + b2.x, a.y + b2.y);
        pmM[tid] = make_float2(a.x - b2.x, a.y - b2.y);
    }
    __syncthreads();
    #pragma unroll
    for (int r = 0; r < 2; ++r) {
        int j = tid + r * 256;
        int y = j >> 3, kt = j & 7;
        float2 A0 = s[kt], A8 = s[64 + kt];
        float2 w8 = tw[(8 * y) & 63];
        float sr = A0.x + A8.x * w8.x + A8.y * w8.y;
        float si = A0.y + A8.y * w8.x - A8.x * w8.y;
        #pragma unroll
        for (int jj = 1; jj < 8; ++jj) {
            float2 w = tw[(jj * y) & 63];
            float2 P = pmP[(jj - 1) * 8 + kt], M = pmM[(jj - 1) * 8 + kt];
            sr += P.x * w.x - M.y * w.y;
            si += P.y * w.x + M.x * w.y;
        }
        T5[((long)bc * 64 + y) * 128 + kx * 8 + kt] = make_float2(sr, si);
    }
}

// ------- inverse x (P/M pairing): T2 space -> T1 space (T6) -------
__global__ __launch_bounds__(256) void k_invx(const float2* __restrict__ T5, float2* __restrict__ T6) {
    __shared__ float2 s[128];
    __shared__ float2 tw[64];
    __shared__ float2 pmP[56], pmM[56];
    int g = blockIdx.x;              // bc*64 + y ; 16384 blocks
    int tid = threadIdx.x;
    if (tid < 128) {
        s[tid] = T5[(long)g * 128 + tid];
    } else if (tid < 192) {
        int m = tid - 128; float sn, cs; __sincosf(m * (TWO_PI / 64.0f), &sn, &cs); tw[m] = make_float2(cs, sn);
    }
    __syncthreads();
    if (tid < 56) {
        int j = (tid >> 3) + 1, kt = tid & 7;
        float2 a = s[j * 8 + kt], b2 = s[(16 - j) * 8 + kt];
        pmP[tid] = make_float2(a.x + b2.x, a.y + b2.y);
        pmM[tid] = make_float2(a.x - b2.x, a.y - b2.y);
    }
    __syncthreads();
    #pragma unroll
    for (int r = 0; r < 2; ++r) {
        int j = tid + r * 256;
        int x = j >> 3, kt = j & 7;
        float2 A0 = s[kt], A8 = s[64 + kt];
        float2 w8 = tw[(8 * x) & 63];
        float sr = A0.x + A8.x * w8.x + A8.y * w8.y;
        float si = A0.y + A8.y * w8.x - A8.x * w8.y;
        #pragma unroll
        for (int jj = 1; jj < 8; ++jj) {
            float2 w = tw[(jj * x) & 63];
            float2 P = pmP[(jj - 1) * 8 + kt], M = pmM[(jj - 1) * 8 + kt];
            sr += P.x * w.x - M.y * w.y;
            si += P.y * w.x + M.x * w.y;
        }
        T6[(long)g * 512 + j] = make_float2(sr, si);
    }
}

// ---- fuse3: MFMA pointwise + E/O spec + gelu2; X update; E/O Goertzel -> T1 ----
__global__ __launch_bounds__(256) void k_fuse3(float* __restrict__ X, const float2* __restrict__ T6,
                                               const float* __restrict__ pww,
                                               const float* __restrict__ pwb,
                                               float2* __restrict__ T1, int layer) {
    __shared__ float smem[9216];     // ts 4224 f (rows 66 f2) / xs 256 rows x 36
    float2* ts = (float2*)smem;
    int g = blockIdx.x;              // b*512 + spt ; 4096 blocks
    int spt = g & 511, b = g >> 9;
    int sp0 = spt * 8;
    int tid = threadIdx.x;
    {   // stage spectral tile pre-scaled: ts[o*66 + spl*8 + kt]
        int o = tid >> 3, spl = tid & 7;
        const float4* src = (const float4*)(T6 + ((long)(b * 32 + o) * 4096 + sp0 + spl) * 8);
        float4* dst = (float4*)(ts + o * 66 + spl * 8);
        const float S = 1.0f / 131072.0f;
        #pragma unroll
        for (int j = 0; j < 4; ++j) {
            float4 q = src[j];
            dst[j] = make_float4(q.x * S, q.y * S, q.z * S, q.w * S);
        }
    }
    int wave = tid >> 6, lane = tid & 63, l15 = lane & 15, quad = lane >> 4;
    int wb = wave * 64;
    const float* wl = pww + layer * 1024;
    const float* bl = pwb + layer * 32;
    bf16x8 wah[2], wal[2];
    f32x4 acc[2][4];
    #pragma unroll
    for (int mt = 0; mt < 2; ++mt) {
        const float4* p = (const float4*)(wl + (mt * 16 + l15) * 32 + quad * 8);
        split8(p[0], p[1], wah[mt], wal[mt]);
        float4 bv = *(const float4*)(bl + mt * 16 + quad * 4);
        f32x4 bi; bi[0] = bv.x; bi[1] = bv.y; bi[2] = bv.z; bi[3] = bv.w;
        #pragma unroll
        for (int nt = 0; nt < 4; ++nt) acc[mt][nt] = bi;
    }
    #pragma unroll
    for (int nt = 0; nt < 4; ++nt) {
        int pt = wb + nt * 16 + l15;
        int spl = pt >> 5, t = pt & 31;
        const float4* xp = (const float4*)(X + (((long)(b * 4096 + sp0 + spl)) * 32 + t) * 32 + quad * 8);
        bf16x8 bh, blo; split8(xp[0], xp[1], bh, blo);
        #pragma unroll
        for (int mt = 0; mt < 2; ++mt) {
            acc[mt][nt] = mfma16(wah[mt], bh, acc[mt][nt]);
            acc[mt][nt] = mfma16(wal[mt], bh, acc[mt][nt]);
            acc[mt][nt] = mfma16(wah[mt], blo, acc[mt][nt]);
        }
    }
    __syncthreads();                 // ts fully staged
    MAKE_TWIDDLES(l15)
    #pragma unroll
    for (int mt = 0; mt < 2; ++mt)
        #pragma unroll
        for (int reg = 0; reg < 4; ++reg) {
            int o = mt * 16 + quad * 4 + reg;
            #pragma unroll
            for (int sph = 0; sph < 2; ++sph) {
                const float4* f4 = (const float4*)(ts + o * 66 + (2 * wave + sph) * 8);
                float4 q0 = f4[0], q1f = f4[1], q2f = f4[2], q3f = f4[3];
                float E = q0.x + q1f.x * ck2[2] - q1f.y * sk2[2]
                        + q2f.x * ck2[4] - q2f.y * sk2[4]
                        + q3f.x * ck2[6] - q3f.y * sk2[6];
                float O = q0.z * ck2[1] - q0.w * sk2[1]
                        + q1f.z * ck2[3] - q1f.w * sk2[3]
                        + q2f.z * ck2[5] - q2f.w * sk2[5]
                        + q3f.z * ck2[7] - q3f.w * sk2[7];
                acc[mt][sph * 2 + 0][reg] += E + O;
                acc[mt][sph * 2 + 1][reg] += E - O;
            }
        }
    #pragma unroll
    for (int mt = 0; mt < 2; ++mt)
        #pragma unroll
        for (int nt = 0; nt < 4; ++nt) gelu4(acc[mt][nt]);
    __syncthreads();                 // ts reads done; smem becomes xs
    #pragma unroll
    for (int mt = 0; mt < 2; ++mt)
        #pragma unroll
        for (int nt = 0; nt < 4; ++nt) {
            int pt = wb + nt * 16 + l15;
            int spl = pt >> 5, t = pt & 31;
            int o0 = mt * 16 + quad * 4;
            float4 w4 = make_float4(acc[mt][nt][0], acc[mt][nt][1], acc[mt][nt][2], acc[mt][nt][3]);
            *(float4*)(X + (((long)(b * 4096 + sp0 + spl)) * 32 + t) * 32 + o0) = w4;
            *(float4*)(smem + (spl * 32 + t) * 36 + o0) = w4;
        }
    __syncthreads();
    // E/O Goertzel t-DFT for next layer
    int c = tid & 31, sl = tid >> 5;
    const float* col = smem + (sl * 32) * 36 + c;
    float2* ob = T1 + ((long)(b * 32 + c) * 4096 + sp0 + sl) * 8;
    GOERTZEL_EO(col, 36, ob)
}

// ---- fuse3_last: MFMA layer-3 pointwise + MFMA q1 head + VALU q2 -> out ----
__global__ __launch_bounds__(256) void k_fuse3_last(const float* __restrict__ X, const float2* __restrict__ T6,
                                                    const float* __restrict__ pww, const float* __restrict__ pwb,
                                                    const float* __restrict__ q1w, const float* __restrict__ q1b,
                                                    const float* __restrict__ q2w, const float* __restrict__ q2b,
                                                    float* __restrict__ out) {
    __shared__ float smem[9408];     // ts 4224 / acts 256x36 (union); q2w at 9216
    float2* ts = (float2*)smem;
    int g = blockIdx.x;              // b*512 + spt ; 4096 blocks
    int spt = g & 511, b = g >> 9;
    int sp0 = spt * 8;
    int tid = threadIdx.x;
    {
        int o = tid >> 3, spl = tid & 7;
        const float4* src = (const float4*)(T6 + ((long)(b * 32 + o) * 4096 + sp0 + spl) * 8);
        float4* dst = (float4*)(ts + o * 66 + spl * 8);
        const float S = 1.0f / 131072.0f;
        #pragma unroll
        for (int j = 0; j < 4; ++j) {
            float4 q = src[j];
            dst[j] = make_float4(q.x * S, q.y * S, q.z * S, q.w * S);
        }
    }
    if (tid < 192) smem[9216 + tid] = q2w[tid];
    int wave = tid >> 6, lane = tid & 63, l15 = lane & 15, quad = lane >> 4;
    int wb = wave * 64;
    const float* wl = pww + 3 * 1024;
    const float* bl = pwb + 3 * 32;
    bf16x8 wah[2], wal[2];
    f32x4 acc[2][4];
    #pragma unroll
    for (int mt = 0; mt < 2; ++mt) {
        const float4* p = (const float4*)(wl + (mt * 16 + l15) * 32 + quad * 8);
        split8(p[0], p[1], wah[mt], wal[mt]);
        float4 bv = *(const float4*)(bl + mt * 16 + quad * 4);
        f32x4 bi; bi[0] = bv.x; bi[1] = bv.y; bi[2] = bv.z; bi[3] = bv.w;
        #pragma unroll
        for (int nt = 0; nt < 4; ++nt) acc[mt][nt] = bi;
    }
    #pragma unroll
    for (int nt = 0; nt < 4; ++nt) {
        int pt = wb + nt * 16 + l15;
        int spl = pt >> 5, t = pt & 31;
        const float4* xp = (const float4*)(X + (((long)(b * 4096 + sp0 + spl)) * 32 + t) * 32 + quad * 8);
        bf16x8 bh, blo; split8(xp[0], xp[1], bh, blo);
        #pragma unroll
        for (int mt = 0; mt < 2; ++mt) {
            acc[mt][nt] = mfma16(wah[mt], bh, acc[mt][nt]);
            acc[mt][nt] = mfma16(wal[mt], bh, acc[mt][nt]);
            acc[mt][nt] = mfma16(wah[mt], blo, acc[mt][nt]);
        }
    }
    __syncthreads();
    MAKE_TWIDDLES(l15)
    #pragma unroll
    for (int mt = 0; mt < 2; ++mt)
        #pragma unroll
        for (int reg = 0; reg < 4; ++reg) {
            int o = mt * 16 + quad * 4 + reg;
            #pragma unroll
            for (int sph = 0; sph < 2; ++sph) {
                const float4* f4 = (const float4*)(ts + o * 66 + (2 * wave + sph) * 8);
                float4 q0 = f4[0], q1f = f4[1], q2f = f4[2], q3f = f4[3];
                float E = q0.x + q1f.x * ck2[2] - q1f.y * sk2[2]
                        + q2f.x * ck2[4] - q2f.y * sk2[4]
                        + q3f.x * ck2[6] - q3f.y * sk2[6];
                float O = q0.z * ck2[1] - q0.w * sk2[1]
                        + q1f.z * ck2[3] - q1f.w * sk2[3]
                        + q2f.z * ck2[5] - q2f.w * sk2[5]
                        + q3f.z * ck2[7] - q3f.w * sk2[7];
                acc[mt][sph * 2 + 0][reg] += E + O;
                acc[mt][sph * 2 + 1][reg] += E - O;
            }
        }
    #pragma unroll
    for (int mt = 0; mt < 2; ++mt)
        #pragma unroll
        for (int nt = 0; nt < 4; ++nt) gelu4(acc[mt][nt]);
    __syncthreads();                 // ts reads done; smem[0..9215] becomes acts[pt][36]
    #pragma unroll
    for (int mt = 0; mt < 2; ++mt)
        #pragma unroll
        for (int nt = 0; nt < 4; ++nt) {
            int pt = wb + nt * 16 + l15;
            int o0 = mt * 16 + quad * 4;
            *(float4*)(smem + pt * 36 + o0) =
                make_float4(acc[mt][nt][0], acc[mt][nt][1], acc[mt][nt][2], acc[mt][nt][3]);
        }
    __syncthreads();
    // head: q1 (MFMA) + gelu2 + q2 (lane-local + shfl reduce)
    bf16x8 qah[4], qal[4];
    f32x4 qbv[4];
    #pragma unroll
    for (int mt = 0; mt < 4; ++mt) {
        const float4* p = (const float4*)(q1w + (mt * 16 + l15) * 32 + quad * 8);
        split8(p[0], p[1], qah[mt], qal[mt]);
        float4 bv = *(const float4*)(q1b + mt * 16 + quad * 4);
        qbv[mt][0] = bv.x; qbv[mt][1] = bv.y; qbv[mt][2] = bv.z; qbv[mt][3] = bv.w;
    }
    const float* q2l = smem + 9216;
    float q2b0 = q2b[0], q2b1 = q2b[1], q2b2 = q2b[2];
    float oc0[4], oc1[4], oc2[4];
    #pragma unroll
    for (int nt = 0; nt < 4; ++nt) {
        int pt = wb + nt * 16 + l15;
        const float4* bp = (const float4*)(smem + pt * 36 + quad * 8);
        bf16x8 bh, blo; split8(bp[0], bp[1], bh, blo);
        float p0 = 0.f, p1 = 0.f, p2 = 0.f;
        #pragma unroll
        for (int mt = 0; mt < 4; ++mt) {
            f32x4 h = qbv[mt];
            h = mfma16(qah[mt], bh, h);
            h = mfma16(qal[mt], bh, h);
            h = mfma16(qah[mt], blo, h);
            gelu4(h);
            #pragma unroll
            for (int reg = 0; reg < 4; ++reg) {
                int hh = mt * 16 + quad * 4 + reg;
                p0 += q2l[hh] * h[reg];
                p1 += q2l[64 + hh] * h[reg];
                p2 += q2l[128 + hh] * h[reg];
            }
        }
        p0 += __shfl_xor(p0, 16); p0 += __shfl_xor(p0, 32);
        p1 += __shfl_xor(p1, 16); p1 += __shfl_xor(p1, 32);
        p2 += __shfl_xor(p2, 16); p2 += __shfl_xor(p2, 32);
        oc0[nt] = p0 + q2b0; oc1[nt] = p1 + q2b1; oc2[nt] = p2 + q2b2;
    }
    __syncthreads();                 // act reads done; smem[0..863] becomes out-stage
    if (quad == 0) {
        #pragma unroll
        for (int nt = 0; nt < 4; ++nt) {
            int pt = wb + nt * 16 + l15;
            int spl = pt >> 5, t = pt & 31;
            smem[(t * 3 + 0) * 9 + spl] = oc0[nt];
            smem[(t * 3 + 1) * 9 + spl] = oc1[nt];
            smem[(t * 3 + 2) * 9 + spl] = oc2[nt];
        }
    }
    __syncthreads();
    for (int m = tid; m < 768; m += 256) {
        int u = m >> 3, spl = m & 7;
        out[((long)(b * 96 + u)) * 4096 + sp0 + spl] = smem[u * 9 + spl];
    }
}

extern "C" void kernel_launch(void* const* d_in, const int* in_sizes, int n_in,
                              void* d_out, int out_size, void* d_ws, size_t ws_size,
                              hipStream_t stream) {
    const float* xt  = (const float*)d_in[0];
    const float* pw  = (const float*)d_in[1];
    const float* pb  = (const float*)d_in[2];
    const float* swr = (const float*)d_in[3];
    const float* swi = (const float*)d_in[4];
    const float* pww = (const float*)d_in[5];
    const float* pwb = (const float*)d_in[6];
    const float* q1w = (const float*)d_in[7];
    const float* q1b = (const float*)d_in[8];
    const float* q2w = (const float*)d_in[9];
    const float* q2b = (const float*)d_in[10];
    float* out = (float*)d_out;

    float*  X  = (float*)d_ws;
    float2* T1 = (float2*)(X + 33554432);
    float2* T2 = (float2*)((float*)T1 + 16777216);
    float2* T3 = (float2*)((float*)T2 + 4194304);
    float2* T4 = (float2*)((float*)T3 + 1048576);

    k_lift<<<4096, 256, 0, stream>>>(xt, pw, pb, X, T1);
    for (int l = 0; l < 4; ++l) {
        k_xdft<<<8192, 256, 0, stream>>>(T1, T2);
        k_ydft<<<4096, 128, 0, stream>>>(T2, T3);
        k_mix2<<<256, 256, 0, stream>>>(T3, swr, swi, T4, l);
        k_invy<<<4096, 256, 0, stream>>>(T4, T2);
        k_invx<<<16384, 256, 0, stream>>>(T2, T1);
        if (l < 3)
            k_fuse3<<<4096, 256, 0, stream>>>(X, T1, pww, pwb, T1, l);
        else
            k_fuse3_last<<<4096, 256, 0, stream>>>(X, T1, pww, pwb, q1w, q1b, q2w, q2b, out);
    }
}